// Round 1
// baseline (117.617 us; speedup 1.0000x reference)
//
#include <hip/hip_runtime.h>

// MultiHeadDense: out[b] = x[b] @ W[idx[b]] + bias[idx[b]]
// B=4096, D=1024, F=1024, H=8. fp32 in/out; bf16 MFMA internally.

#define BDIM 4096
#define DDIM 1024
#define FDIM 1024
#define HDIM 8

typedef __attribute__((ext_vector_type(8))) short bf16x8;
typedef __attribute__((ext_vector_type(4))) float f32x4;

static __device__ __forceinline__ unsigned short f2bf(float f) {
  union { float f; unsigned int u; } c; c.f = f;
  unsigned int u = c.u;
  return (unsigned short)((u + 0x7fffu + ((u >> 16) & 1u)) >> 16);
}

static __device__ __forceinline__ void gload16(const void* g, void* s) {
  __builtin_amdgcn_global_load_lds(
      (const __attribute__((address_space(1))) void*)g,
      (__attribute__((address_space(3))) void*)s, 16, 0, 0);
}

// Kernel 1: transpose+convert W [H][D][F] fp32 -> Wt [H][F][D] bf16,
// and count rows per head (first 16 blocks).
__global__ __launch_bounds__(256) void k_prep(
    const float* __restrict__ W, const int* __restrict__ idx,
    unsigned short* __restrict__ Wt, int* __restrict__ cnt) {
  __shared__ unsigned short tile[32][33];
  __shared__ int hcnt[8];
  const int t = threadIdx.x;
  const int h = blockIdx.z, d0 = blockIdx.y * 32, f0 = blockIdx.x * 32;

  const bool counting = (blockIdx.z == 0 && blockIdx.y == 0 && blockIdx.x < 16);
  if (counting) {
    if (t < 8) hcnt[t] = 0;
    __syncthreads();
    atomicAdd(&hcnt[idx[blockIdx.x * 256 + t]], 1);
  }

  const int dr = t >> 3, fc = (t & 7) * 4;
  const float4 v = *(const float4*)(W + (size_t)(h * 1024 + d0 + dr) * 1024 + f0 + fc);
  tile[dr][fc + 0] = f2bf(v.x);
  tile[dr][fc + 1] = f2bf(v.y);
  tile[dr][fc + 2] = f2bf(v.z);
  tile[dr][fc + 3] = f2bf(v.w);
  __syncthreads();

  if (counting && t < 8) atomicAdd(&cnt[t], hcnt[t]);

  const int fr = t >> 3, dc = (t & 7) * 4;
  ushort4 o;
  o.x = tile[dc + 0][fr];
  o.y = tile[dc + 1][fr];
  o.z = tile[dc + 2][fr];
  o.w = tile[dc + 3][fr];
  *(ushort4*)(Wt + (size_t)(h * 1024 + f0 + fr) * 1024 + d0 + dc) = o;
}

// Kernel 2: bin rows by head; gather x row b -> packed bf16 A at slot, record rows[slot]=b.
__global__ __launch_bounds__(256) void k_pack(
    const float* __restrict__ X, const int* __restrict__ idx,
    const int* __restrict__ cnt, int* __restrict__ cur,
    int* __restrict__ rows, unsigned short* __restrict__ Ap) {
  const int b = blockIdx.x;
  __shared__ int sslot;
  if (threadIdx.x == 0) {
    const int h = idx[b];
    int base = 0;
    for (int i = 0; i < 8; ++i) base += (i < h) ? cnt[i] : 0;
    const int pos = atomicAdd(&cur[h], 1);
    const int slot = base + pos;
    rows[slot] = b;
    sslot = slot;
  }
  __syncthreads();
  const int slot = sslot;
  const int t = threadIdx.x;
  const float4 v = *(const float4*)(X + (size_t)b * 1024 + t * 4);
  ushort4 o;
  o.x = f2bf(v.x); o.y = f2bf(v.y); o.z = f2bf(v.z); o.w = f2bf(v.w);
  *(ushort4*)(Ap + (size_t)slot * 1024 + t * 4) = o;
}

// Kernel 3: grouped GEMM. Per head h: X_h [cnt_h x 1024] @ W_h^T-layout -> out rows.
// 128x128 tile, BK=32, 4 waves (2x2), mfma 16x16x32 bf16, dbuf LDS + global_load_lds.
__global__ __launch_bounds__(256) void k_gemm(
    const unsigned short* __restrict__ Ap, const unsigned short* __restrict__ Wt,
    const int* __restrict__ rows, const int* __restrict__ cnt,
    const float* __restrict__ bias, float* __restrict__ out) {
  __shared__ __align__(16) unsigned short As[2][128 * 32];
  __shared__ __align__(16) unsigned short Bs[2][128 * 32];

  const int h = blockIdx.z;
  int cnt_h = 0, basep = 0;
#pragma unroll
  for (int i = 0; i < 8; ++i) {
    const int c = cnt[i];
    basep += (i < h) ? c : 0;
    if (i == h) cnt_h = c;
  }
  const int m0 = blockIdx.y * 128;
  if (m0 >= cnt_h) return;
  const int n0 = blockIdx.x * 128;

  const int tid = threadIdx.x;
  const int lane = tid & 63;
  const int wave = tid >> 6;
  const int wr = wave >> 1, wc = wave & 1;

  const char* Ag = (const char*)(Ap + (size_t)(basep + m0) * 1024);
  const char* Bg = (const char*)(Wt + ((size_t)h * 1024 + n0) * 1024);
  const int srow = tid >> 2;           // 0..63: tile row within 64-row half
  const int scol = (tid & 3) * 16;     // byte offset within 64B row

  f32x4 acc[4][4];
#pragma unroll
  for (int m = 0; m < 4; ++m)
#pragma unroll
    for (int n = 0; n < 4; ++n)
      acc[m][n] = (f32x4){0.f, 0.f, 0.f, 0.f};

  auto stage = [&](int s, int k0) {
#pragma unroll
    for (int i = 0; i < 2; ++i) {
      gload16(Ag + (size_t)(i * 64 + srow) * 2048 + k0 * 2 + scol,
              (char*)(&As[s][0]) + i * 4096 + wave * 1024);
      gload16(Bg + (size_t)(i * 64 + srow) * 2048 + k0 * 2 + scol,
              (char*)(&Bs[s][0]) + i * 4096 + wave * 1024);
    }
  };

  // LDS frag read offsets (bytes): row * 64 + kgroup*16
  const int rla = (wr * 64 + (lane & 15)) * 64 + (lane >> 4) * 16;
  const int rlb = (wc * 64 + (lane & 15)) * 64 + (lane >> 4) * 16;

  stage(0, 0);
  __syncthreads();

  for (int t = 0; t < 32; ++t) {
    const int s = t & 1;
    if (t < 31) stage(s ^ 1, (t + 1) * 32);
    bf16x8 af[4], bf[4];
#pragma unroll
    for (int m = 0; m < 4; ++m)
      af[m] = *(const bf16x8*)((const char*)(&As[s][0]) + rla + m * 1024);
#pragma unroll
    for (int n = 0; n < 4; ++n)
      bf[n] = *(const bf16x8*)((const char*)(&Bs[s][0]) + rlb + n * 1024);
#pragma unroll
    for (int m = 0; m < 4; ++m)
#pragma unroll
      for (int n = 0; n < 4; ++n)
        acc[m][n] = __builtin_amdgcn_mfma_f32_16x16x32_bf16(af[m], bf[n], acc[m][n], 0, 0, 0);
    __syncthreads();
  }

  // Epilogue: scatter rows through rows[] map, add bias (fp32).
  int rmap[4][4];
  bool vld[4][4];
#pragma unroll
  for (int m = 0; m < 4; ++m) {
#pragma unroll
    for (int j = 0; j < 4; ++j) {
      const int lr = wr * 64 + m * 16 + (lane >> 4) * 4 + j;
      const bool v = (m0 + lr) < cnt_h;
      vld[m][j] = v;
      rmap[m][j] = v ? rows[basep + m0 + lr] : 0;
    }
  }
#pragma unroll
  for (int n = 0; n < 4; ++n) {
    const int c = n0 + wc * 64 + n * 16 + (lane & 15);
    const float bv = bias[h * 1024 + c];
#pragma unroll
    for (int m = 0; m < 4; ++m) {
#pragma unroll
      for (int j = 0; j < 4; ++j) {
        if (vld[m][j])
          out[(size_t)rmap[m][j] * 1024 + c] = acc[m][n][j] + bv;
      }
    }
  }
}

extern "C" void kernel_launch(void* const* d_in, const int* in_sizes, int n_in,
                              void* d_out, int out_size, void* d_ws, size_t ws_size,
                              hipStream_t stream) {
  const float* X = (const float*)d_in[0];
  const int* idx = (const int*)d_in[1];
  const float* W = (const float*)d_in[2];
  const float* bias = (const float*)d_in[3];
  float* out = (float*)d_out;

  char* ws = (char*)d_ws;
  int* cnt = (int*)ws;                                   // 8 ints
  int* cur = (int*)(ws + 32);                            // 8 ints
  int* rows = (int*)(ws + 256);                          // 4096 ints
  unsigned short* Wt = (unsigned short*)(ws + 32768);    // 8*1024*1024 bf16 = 16 MB
  unsigned short* Ap = (unsigned short*)(ws + 32768 + 16777216);  // (4096+128)*1024 bf16

  hipMemsetAsync(ws, 0, 64, stream);  // zero cnt + cur
  k_prep<<<dim3(32, 32, 8), 256, 0, stream>>>(W, idx, Wt, cnt);
  k_pack<<<dim3(4096), 256, 0, stream>>>(X, idx, cnt, cur, rows, Ap);
  k_gemm<<<dim3(8, 32, 8), 256, 0, stream>>>(Ap, Wt, rows, cnt, bias, out);
}

// Round 2
// 73.717 us; speedup vs baseline: 1.5955x; 1.5955x over previous
//
#include <hip/hip_runtime.h>

// MultiHeadDense: out[b] = x[b] @ W[idx[b]] + bias[idx[b]]
// B=4096, D=1024, F=1024, H=8. fp32 in/out; bf16 MFMA internally.
// Pipeline: k_prep (W transpose->bf16 + scan-based row binning, no atomics)
//           k_gather (permuted X copy fp32->bf16)
//           k_gemm (grouped 128x128 MFMA GEMM, scatter epilogue + bias)

typedef __attribute__((ext_vector_type(8))) short bf16x8;
typedef __attribute__((ext_vector_type(4))) float f32x4;

static __device__ __forceinline__ unsigned short f2bf(float f) {
  union { float f; unsigned int u; } c; c.f = f;
  unsigned int u = c.u;
  return (unsigned short)((u + 0x7fffu + ((u >> 16) & 1u)) >> 16);
}

static __device__ __forceinline__ void gload16(const void* g, void* s) {
  __builtin_amdgcn_global_load_lds(
      (const __attribute__((address_space(1))) void*)g,
      (__attribute__((address_space(3))) void*)s, 16, 0, 0);
}

// Kernel 1 (fused): blocks 0..2047 transpose+convert W [H][D][F] fp32 ->
// Wt [H][F][D] bf16 in 64x64 tiles. Block 2048: deterministic counting-sort
// scan of idx -> rows[] (stable partition by head) + cnt[]. No atomics.
__global__ __launch_bounds__(256) void k_prep(
    const float* __restrict__ W, const int* __restrict__ idx,
    unsigned short* __restrict__ Wt, int* __restrict__ cnt,
    int* __restrict__ rows) {
  const int bid = blockIdx.x;
  const int t = threadIdx.x;

  if (bid >= 2048) {
    // ---- scan block: stable counting sort of 4096 indices into 8 bins ----
    __shared__ int sc[256][8];
    int myi[16];
#pragma unroll
    for (int i = 0; i < 4; ++i) {
      const int4 v = *(const int4*)(idx + t * 16 + i * 4);
      myi[i * 4 + 0] = v.x; myi[i * 4 + 1] = v.y;
      myi[i * 4 + 2] = v.z; myi[i * 4 + 3] = v.w;
    }
    int c[8];
#pragma unroll
    for (int h = 0; h < 8; ++h) c[h] = 0;
#pragma unroll
    for (int e = 0; e < 16; ++e)
#pragma unroll
      for (int h = 0; h < 8; ++h) c[h] += (myi[e] == h) ? 1 : 0;

    int val[8];
#pragma unroll
    for (int h = 0; h < 8; ++h) { val[h] = c[h]; sc[t][h] = c[h]; }
    __syncthreads();
    for (int off = 1; off < 256; off <<= 1) {
      int nb[8];
#pragma unroll
      for (int h = 0; h < 8; ++h) nb[h] = (t >= off) ? sc[t - off][h] : 0;
      __syncthreads();
#pragma unroll
      for (int h = 0; h < 8; ++h) { val[h] += nb[h]; sc[t][h] = val[h]; }
      __syncthreads();
    }
    int tot[8], base[8], excl[8];
#pragma unroll
    for (int h = 0; h < 8; ++h) tot[h] = sc[255][h];
    int a = 0;
#pragma unroll
    for (int h = 0; h < 8; ++h) { base[h] = a; a += tot[h]; }
#pragma unroll
    for (int h = 0; h < 8; ++h) excl[h] = val[h] - c[h];
    // emit slots; per-head pass keeps all register indexing compile-time
#pragma unroll
    for (int h = 0; h < 8; ++h) {
      int pos = base[h] + excl[h];
#pragma unroll
      for (int e = 0; e < 16; ++e) {
        if (myi[e] == h) { rows[pos] = t * 16 + e; ++pos; }
      }
    }
    if (t < 8) cnt[t] = tot[t];
    return;
  }

  // ---- transpose block: 64x64 tile of head h ----
  __shared__ unsigned short tile[64][68];
  const int h = bid >> 8;
  const int rem = bid & 255;
  const int d0 = (rem >> 4) << 6;
  const int f0 = (rem & 15) << 6;
  const int c4 = (t & 15) * 4;
  const int r0 = t >> 4;
#pragma unroll
  for (int i = 0; i < 4; ++i) {
    const int r = r0 + i * 16;
    const float4 v = *(const float4*)(W + (size_t)(h * 1024 + d0 + r) * 1024 + f0 + c4);
    tile[r][c4 + 0] = f2bf(v.x);
    tile[r][c4 + 1] = f2bf(v.y);
    tile[r][c4 + 2] = f2bf(v.z);
    tile[r][c4 + 3] = f2bf(v.w);
  }
  __syncthreads();
#pragma unroll
  for (int i = 0; i < 4; ++i) {
    const int fr = r0 + i * 16;
    ushort4 o;
    o.x = tile[c4 + 0][fr];
    o.y = tile[c4 + 1][fr];
    o.z = tile[c4 + 2][fr];
    o.w = tile[c4 + 3][fr];
    *(ushort4*)(Wt + (size_t)(h * 1024 + f0 + fr) * 1024 + d0 + c4) = o;
  }
}

// Kernel 2: permuted gather-copy X row rows[slot] -> Ap[slot], fp32->bf16.
__global__ __launch_bounds__(256) void k_gather(
    const float* __restrict__ X, const int* __restrict__ rows,
    unsigned short* __restrict__ Ap) {
  const int slot = blockIdx.x;
  const int b = rows[slot];
  const int t = threadIdx.x;
  const float4 v = *(const float4*)(X + (size_t)b * 1024 + t * 4);
  ushort4 o;
  o.x = f2bf(v.x); o.y = f2bf(v.y); o.z = f2bf(v.z); o.w = f2bf(v.w);
  *(ushort4*)(Ap + (size_t)slot * 1024 + t * 4) = o;
}

// Kernel 3: grouped GEMM. Per head h: Ap rows [cnt_h x 1024] @ Wt_h -> out.
// 128x128 tile, BK=32, 4 waves (2x2), mfma 16x16x32 bf16, dbuf LDS + global_load_lds.
__global__ __launch_bounds__(256) void k_gemm(
    const unsigned short* __restrict__ Ap, const unsigned short* __restrict__ Wt,
    const int* __restrict__ rows, const int* __restrict__ cnt,
    const float* __restrict__ bias, float* __restrict__ out) {
  __shared__ __align__(16) unsigned short As[2][128 * 32];
  __shared__ __align__(16) unsigned short Bs[2][128 * 32];

  const int h = blockIdx.z;
  int cnt_h = 0, basep = 0;
#pragma unroll
  for (int i = 0; i < 8; ++i) {
    const int c = cnt[i];
    basep += (i < h) ? c : 0;
    if (i == h) cnt_h = c;
  }
  const int m0 = blockIdx.y * 128;
  if (m0 >= cnt_h) return;
  const int n0 = blockIdx.x * 128;

  const int tid = threadIdx.x;
  const int lane = tid & 63;
  const int wave = tid >> 6;
  const int wr = wave >> 1, wc = wave & 1;

  const char* Ag = (const char*)(Ap + (size_t)(basep + m0) * 1024);
  const char* Bg = (const char*)(Wt + ((size_t)h * 1024 + n0) * 1024);
  const int srow = tid >> 2;           // 0..63: tile row within 64-row half
  const int scol = (tid & 3) * 16;     // byte offset within 64B row

  f32x4 acc[4][4];
#pragma unroll
  for (int m = 0; m < 4; ++m)
#pragma unroll
    for (int n = 0; n < 4; ++n)
      acc[m][n] = (f32x4){0.f, 0.f, 0.f, 0.f};

  auto stage = [&](int s, int k0) {
#pragma unroll
    for (int i = 0; i < 2; ++i) {
      gload16(Ag + (size_t)(i * 64 + srow) * 2048 + k0 * 2 + scol,
              (char*)(&As[s][0]) + i * 4096 + wave * 1024);
      gload16(Bg + (size_t)(i * 64 + srow) * 2048 + k0 * 2 + scol,
              (char*)(&Bs[s][0]) + i * 4096 + wave * 1024);
    }
  };

  const int rla = (wr * 64 + (lane & 15)) * 64 + (lane >> 4) * 16;
  const int rlb = (wc * 64 + (lane & 15)) * 64 + (lane >> 4) * 16;

  stage(0, 0);
  __syncthreads();

  for (int t = 0; t < 32; ++t) {
    const int s = t & 1;
    if (t < 31) stage(s ^ 1, (t + 1) * 32);
    bf16x8 af[4], bfr[4];
#pragma unroll
    for (int m = 0; m < 4; ++m)
      af[m] = *(const bf16x8*)((const char*)(&As[s][0]) + rla + m * 1024);
#pragma unroll
    for (int n = 0; n < 4; ++n)
      bfr[n] = *(const bf16x8*)((const char*)(&Bs[s][0]) + rlb + n * 1024);
#pragma unroll
    for (int m = 0; m < 4; ++m)
#pragma unroll
      for (int n = 0; n < 4; ++n)
        acc[m][n] = __builtin_amdgcn_mfma_f32_16x16x32_bf16(af[m], bfr[n], acc[m][n], 0, 0, 0);
    __syncthreads();
  }

  int rmap[4][4];
  bool vld[4][4];
#pragma unroll
  for (int m = 0; m < 4; ++m) {
#pragma unroll
    for (int j = 0; j < 4; ++j) {
      const int lr = wr * 64 + m * 16 + (lane >> 4) * 4 + j;
      const bool v = (m0 + lr) < cnt_h;
      vld[m][j] = v;
      rmap[m][j] = v ? rows[basep + m0 + lr] : 0;
    }
  }
#pragma unroll
  for (int n = 0; n < 4; ++n) {
    const int c = n0 + wc * 64 + n * 16 + (lane & 15);
    const float bv = bias[h * 1024 + c];
#pragma unroll
    for (int m = 0; m < 4; ++m) {
#pragma unroll
      for (int j = 0; j < 4; ++j) {
        if (vld[m][j])
          out[(size_t)rmap[m][j] * 1024 + c] = acc[m][n][j] + bv;
      }
    }
  }
}

extern "C" void kernel_launch(void* const* d_in, const int* in_sizes, int n_in,
                              void* d_out, int out_size, void* d_ws, size_t ws_size,
                              hipStream_t stream) {
  const float* X = (const float*)d_in[0];
  const int* idx = (const int*)d_in[1];
  const float* W = (const float*)d_in[2];
  const float* bias = (const float*)d_in[3];
  float* out = (float*)d_out;

  char* ws = (char*)d_ws;
  int* cnt = (int*)ws;                                   // 8 ints
  int* rows = (int*)(ws + 256);                          // 4096 ints
  unsigned short* Wt = (unsigned short*)(ws + 32768);    // 8*1024*1024 bf16 = 16 MB
  unsigned short* Ap = (unsigned short*)(ws + 32768 + 16777216);  // (4096+128)*1024 bf16

  k_prep<<<dim3(2049), 256, 0, stream>>>(W, idx, Wt, cnt, rows);
  k_gather<<<dim3(4096), 256, 0, stream>>>(X, rows, Ap);
  k_gemm<<<dim3(8, 32, 8), 256, 0, stream>>>(Ap, Wt, rows, cnt, bias, out);
}

// Round 3
// 57.557 us; speedup vs baseline: 2.0435x; 1.2808x over previous
//
#include <hip/hip_runtime.h>

// MultiHeadDense: out[b] = x[b] @ W[idx[b]] + bias[idx[b]]
// B=4096, D=1024, F=1024, H=8. fp32 in/out; bf16 MFMA internally.
// Pipeline: k_prep (W transpose->bf16 + scan-based row binning, no atomics)
//           k_gather (permuted X copy fp32->bf16)
//           k_gemm (grouped 64x64 MFMA GEMM, XOR-swizzled LDS, scatter+bias)

typedef __attribute__((ext_vector_type(8))) short bf16x8;
typedef __attribute__((ext_vector_type(4))) float f32x4;

static __device__ __forceinline__ unsigned short f2bf(float f) {
  union { float f; unsigned int u; } c; c.f = f;
  unsigned int u = c.u;
  return (unsigned short)((u + 0x7fffu + ((u >> 16) & 1u)) >> 16);
}

static __device__ __forceinline__ void gload16(const void* g, void* s) {
  __builtin_amdgcn_global_load_lds(
      (const __attribute__((address_space(1))) void*)g,
      (__attribute__((address_space(3))) void*)s, 16, 0, 0);
}

// Kernel 1 (fused): blocks 0..2047 transpose+convert W [H][D][F] fp32 ->
// Wt [H][F][D] bf16 in 64x64 tiles. Block 2048: deterministic counting-sort
// scan of idx -> rows[] (stable partition by head) + cnt[]. No atomics.
__global__ __launch_bounds__(256) void k_prep(
    const float* __restrict__ W, const int* __restrict__ idx,
    unsigned short* __restrict__ Wt, int* __restrict__ cnt,
    int* __restrict__ rows) {
  const int bid = blockIdx.x;
  const int t = threadIdx.x;

  if (bid >= 2048) {
    // ---- scan block: stable counting sort of 4096 indices into 8 bins ----
    __shared__ int sc[256][8];
    int myi[16];
#pragma unroll
    for (int i = 0; i < 4; ++i) {
      const int4 v = *(const int4*)(idx + t * 16 + i * 4);
      myi[i * 4 + 0] = v.x; myi[i * 4 + 1] = v.y;
      myi[i * 4 + 2] = v.z; myi[i * 4 + 3] = v.w;
    }
    int c[8];
#pragma unroll
    for (int h = 0; h < 8; ++h) c[h] = 0;
#pragma unroll
    for (int e = 0; e < 16; ++e)
#pragma unroll
      for (int h = 0; h < 8; ++h) c[h] += (myi[e] == h) ? 1 : 0;

    int val[8];
#pragma unroll
    for (int h = 0; h < 8; ++h) { val[h] = c[h]; sc[t][h] = c[h]; }
    __syncthreads();
    for (int off = 1; off < 256; off <<= 1) {
      int nb[8];
#pragma unroll
      for (int h = 0; h < 8; ++h) nb[h] = (t >= off) ? sc[t - off][h] : 0;
      __syncthreads();
#pragma unroll
      for (int h = 0; h < 8; ++h) { val[h] += nb[h]; sc[t][h] = val[h]; }
      __syncthreads();
    }
    int tot[8], base[8], excl[8];
#pragma unroll
    for (int h = 0; h < 8; ++h) tot[h] = sc[255][h];
    int a = 0;
#pragma unroll
    for (int h = 0; h < 8; ++h) { base[h] = a; a += tot[h]; }
#pragma unroll
    for (int h = 0; h < 8; ++h) excl[h] = val[h] - c[h];
#pragma unroll
    for (int h = 0; h < 8; ++h) {
      int pos = base[h] + excl[h];
#pragma unroll
      for (int e = 0; e < 16; ++e) {
        if (myi[e] == h) { rows[pos] = t * 16 + e; ++pos; }
      }
    }
    if (t < 8) cnt[t] = tot[t];
    return;
  }

  // ---- transpose block: 64x64 tile of head h ----
  __shared__ unsigned short tile[64][68];
  const int h = bid >> 8;
  const int rem = bid & 255;
  const int d0 = (rem >> 4) << 6;
  const int f0 = (rem & 15) << 6;
  const int c4 = (t & 15) * 4;
  const int r0 = t >> 4;
#pragma unroll
  for (int i = 0; i < 4; ++i) {
    const int r = r0 + i * 16;
    const float4 v = *(const float4*)(W + (size_t)(h * 1024 + d0 + r) * 1024 + f0 + c4);
    tile[r][c4 + 0] = f2bf(v.x);
    tile[r][c4 + 1] = f2bf(v.y);
    tile[r][c4 + 2] = f2bf(v.z);
    tile[r][c4 + 3] = f2bf(v.w);
  }
  __syncthreads();
#pragma unroll
  for (int i = 0; i < 4; ++i) {
    const int fr = r0 + i * 16;
    ushort4 o;
    o.x = tile[c4 + 0][fr];
    o.y = tile[c4 + 1][fr];
    o.z = tile[c4 + 2][fr];
    o.w = tile[c4 + 3][fr];
    *(ushort4*)(Wt + (size_t)(h * 1024 + f0 + fr) * 1024 + d0 + c4) = o;
  }
}

// Kernel 2: permuted gather-copy X row rows[slot] -> Ap[slot], fp32->bf16.
__global__ __launch_bounds__(256) void k_gather(
    const float* __restrict__ X, const int* __restrict__ rows,
    unsigned short* __restrict__ Ap) {
  const int slot = blockIdx.x;
  const int b = rows[slot];
  const int t = threadIdx.x;
  const float4 v = *(const float4*)(X + (size_t)b * 1024 + t * 4);
  ushort4 o;
  o.x = f2bf(v.x); o.y = f2bf(v.y); o.z = f2bf(v.z); o.w = f2bf(v.w);
  *(ushort4*)(Ap + (size_t)slot * 1024 + t * 4) = o;
}

// Kernel 3: grouped GEMM, 64x64 tile, BK=64, 4 waves (2x2, each 32x32).
// LDS XOR-swizzled (byte ^= (row&7)<<4), both-sides: linear global_load_lds
// dest + pre-swizzled global source + XOR on the ds_read (rule 21).
// 1D grid, h = blk&7 so each XCD's L2 caches one head's Wt panel (2MB).
__global__ __launch_bounds__(256) void k_gemm(
    const unsigned short* __restrict__ Ap, const unsigned short* __restrict__ Wt,
    const int* __restrict__ rows, const int* __restrict__ cnt,
    const float* __restrict__ bias, float* __restrict__ out) {
  __shared__ __align__(16) unsigned short As[2][64 * 64];
  __shared__ __align__(16) unsigned short Bs[2][64 * 64];

  const int blk = blockIdx.x;
  const int h = blk & 7;          // head -> XCD affinity (round-robin % 8)
  const int rem = blk >> 3;
  const int nt = rem & 15;        // 16 n-tiles of 64
  const int mt = rem >> 4;        // up to 64 m-tiles of 64

  int cnt_h = 0, basep = 0;
#pragma unroll
  for (int i = 0; i < 8; ++i) {
    const int c = cnt[i];
    basep += (i < h) ? c : 0;
    if (i == h) cnt_h = c;
  }
  const int m0 = mt * 64;
  if (m0 >= cnt_h) return;
  const int n0 = nt * 64;

  const int t = threadIdx.x;
  const int lane = t & 63;
  const int wave = t >> 6;
  const int wr = wave >> 1, wc = wave & 1;

  const char* Ag = (const char*)(Ap + (size_t)(basep + m0) * 1024);
  const char* Bg = (const char*)(Wt + ((size_t)h * 1024 + n0) * 1024);

  // staging: thread t, chunk c covers LDS bytes [c*4096 + t*16, +16)
  // row = c*32 + (t>>3); source col pre-swizzled so swizzled read is correct
  const int srow = t >> 3;
  const int scolS = (((t & 7) ^ (srow & 7)) << 4);

  f32x4 acc[2][2];
#pragma unroll
  for (int m = 0; m < 2; ++m)
#pragma unroll
    for (int n = 0; n < 2; ++n)
      acc[m][n] = (f32x4){0.f, 0.f, 0.f, 0.f};

  auto stage = [&](int s, int k0) {
#pragma unroll
    for (int c = 0; c < 2; ++c) {
      const int r = c * 32 + srow;
      gload16(Ag + (size_t)r * 2048 + k0 * 2 + scolS,
              (char*)(&As[s][0]) + c * 4096 + t * 16);
      gload16(Bg + (size_t)r * 2048 + k0 * 2 + scolS,
              (char*)(&Bs[s][0]) + c * 4096 + t * 16);
    }
  };

  // frag read bases: row*128 bytes; col = (ksub*64 + (lane>>4)*16) ^ swz
  const int swz = (lane & 7) << 4;
  const int ra = (wr * 32 + (lane & 15)) * 128;
  const int rb = (wc * 32 + (lane & 15)) * 128;
  const int kc = (lane >> 4) << 4;

  stage(0, 0);
  __syncthreads();

  for (int ks = 0; ks < 16; ++ks) {
    const int s = ks & 1;
    if (ks < 15) stage(s ^ 1, (ks + 1) * 64);
#pragma unroll
    for (int ksub = 0; ksub < 2; ++ksub) {
      const int co = ((ksub * 64) + kc) ^ swz;
      const bf16x8 a0 = *(const bf16x8*)((const char*)(&As[s][0]) + ra + co);
      const bf16x8 a1 = *(const bf16x8*)((const char*)(&As[s][0]) + ra + 2048 + co);
      const bf16x8 b0 = *(const bf16x8*)((const char*)(&Bs[s][0]) + rb + co);
      const bf16x8 b1 = *(const bf16x8*)((const char*)(&Bs[s][0]) + rb + 2048 + co);
      acc[0][0] = __builtin_amdgcn_mfma_f32_16x16x32_bf16(a0, b0, acc[0][0], 0, 0, 0);
      acc[0][1] = __builtin_amdgcn_mfma_f32_16x16x32_bf16(a0, b1, acc[0][1], 0, 0, 0);
      acc[1][0] = __builtin_amdgcn_mfma_f32_16x16x32_bf16(a1, b0, acc[1][0], 0, 0, 0);
      acc[1][1] = __builtin_amdgcn_mfma_f32_16x16x32_bf16(a1, b1, acc[1][1], 0, 0, 0);
    }
    __syncthreads();
  }

  // Epilogue: scatter through rows[] map, add bias (fp32).
  int rmap[2][4];
  bool vld[2][4];
#pragma unroll
  for (int m = 0; m < 2; ++m) {
#pragma unroll
    for (int j = 0; j < 4; ++j) {
      const int lr = wr * 32 + m * 16 + (lane >> 4) * 4 + j;
      const bool v = (m0 + lr) < cnt_h;
      vld[m][j] = v;
      rmap[m][j] = v ? rows[basep + m0 + lr] : 0;
    }
  }
#pragma unroll
  for (int n = 0; n < 2; ++n) {
    const int c = n0 + wc * 32 + n * 16 + (lane & 15);
    const float bv = bias[h * 1024 + c];
#pragma unroll
    for (int m = 0; m < 2; ++m) {
#pragma unroll
      for (int j = 0; j < 4; ++j) {
        if (vld[m][j])
          out[(size_t)rmap[m][j] * 1024 + c] = acc[m][n][j] + bv;
      }
    }
  }
}

extern "C" void kernel_launch(void* const* d_in, const int* in_sizes, int n_in,
                              void* d_out, int out_size, void* d_ws, size_t ws_size,
                              hipStream_t stream) {
  const float* X = (const float*)d_in[0];
  const int* idx = (const int*)d_in[1];
  const float* W = (const float*)d_in[2];
  const float* bias = (const float*)d_in[3];
  float* out = (float*)d_out;

  char* ws = (char*)d_ws;
  int* cnt = (int*)ws;                                   // 8 ints
  int* rows = (int*)(ws + 256);                          // 4096 ints
  unsigned short* Wt = (unsigned short*)(ws + 32768);    // 8*1024*1024 bf16 = 16 MB
  unsigned short* Ap = (unsigned short*)(ws + 32768 + 16777216);  // (4096+128)*1024 bf16

  k_prep<<<dim3(2049), 256, 0, stream>>>(W, idx, Wt, cnt, rows);
  k_gather<<<dim3(4096), 256, 0, stream>>>(X, rows, Ap);
  // 8 heads (xcd-affine) x 16 n-tiles x 64 m-tiles (early-return past cnt_h)
  k_gemm<<<dim3(8 * 16 * 64), 256, 0, stream>>>(Ap, Wt, rows, cnt, bias, out);
}